// Round 1
// baseline (547.105 us; speedup 1.0000x reference)
//
#include <hip/hip_runtime.h>

// ---- types ----
typedef _Float16 half8 __attribute__((ext_vector_type(8)));
typedef _Float16 half4 __attribute__((ext_vector_type(4)));
typedef float    f32x4 __attribute__((ext_vector_type(4)));
typedef float    f4    __attribute__((ext_vector_type(4)));
typedef int      i4    __attribute__((ext_vector_type(4)));

#if defined(__has_builtin)
#if __has_builtin(__builtin_amdgcn_exp2f)
#define EXP2(x) __builtin_amdgcn_exp2f(x)
#else
#define EXP2(x) exp2f(x)
#endif
#else
#define EXP2(x) exp2f(x)
#endif

// ---- problem constants (B=2, S=4096, H=16, D=64) ----
#define S_LEN 4096
#define NHEAD 16
#define HDIM 64
#define ROWSTRIDE 1024          // H*D floats between consecutive s
#define NKITER 64               // S / 64
#define QSCALE 0.18033688011112042f     // (1/sqrt(64)) * log2(e)
#define MASKVAL (-1.4426950408889634e30f) // -1e30 * log2(e), finite
#define LDK 72                  // LDS leading dim (halves): 144B rows, 16B aligned
#define LDP 72

// =======================================================================
// Pre-pass: reduce mask[B,1,S,S] to per-(b, 128-q-tile, 64-k-tile) flags
// flag==1  -> tile is all nonzero (no masking needed)
// =======================================================================
__global__ __launch_bounds__(256)
void fa_maskflags(const int* __restrict__ Mask, unsigned char* __restrict__ Flags)
{
    const int kt = blockIdx.x;   // 0..63
    const int qt = blockIdx.y;   // 0..31
    const int b  = blockIdx.z;   // 0..1
    const int t  = threadIdx.x;
    const int row = qt * 128 + (t >> 1);
    const int col = kt * 64 + (t & 1) * 32;
    const i4* p = (const i4*)(Mask + (size_t)(b * S_LEN + row) * S_LEN + col);
    int bad = 0;
#pragma unroll
    for (int j = 0; j < 8; ++j) {
        i4 m = p[j];
        bad |= (m[0] == 0) | (m[1] == 0) | (m[2] == 0) | (m[3] == 0);
    }
    __shared__ int s_bad;
    if (t == 0) s_bad = 0;
    __syncthreads();
    if (bad) atomicOr(&s_bad, 1);
    __syncthreads();
    if (t == 0) Flags[((size_t)b * 32 + qt) * 64 + kt] = (s_bad == 0) ? 1 : 0;
}

// =======================================================================
// Fused flash-attention forward.
//   grid = 1024 blocks of 256 threads (4 waves); each block: one (b,h) and a
//   128-row Q tile; K-loop over 64-row K/V tiles with online softmax.
// MFMA layouts (verified, 16x16x32):
//   A: A[m=lane&15][k=(lane>>4)*8+j]   B: B[k=(lane>>4)*8+j][n=lane&15]
//   C/D: C[(lane>>4)*4+r][lane&15]
// We compute S^T = K*Q^T (so qi == lane column -> softmax state in-lane) and
// O^T = mfma(V^T-frag, P^T-frag) with P round-tripped via per-wave LDS.
// =======================================================================
__global__ __launch_bounds__(256)
void fa_fwd(const float* __restrict__ Q, const float* __restrict__ K,
            const float* __restrict__ V, const int* __restrict__ Mask,
            const unsigned char* __restrict__ Flags, float* __restrict__ Out)
{
    __shared__ __align__(16) _Float16 sK[64 * LDK];      // [kj][d]
    __shared__ __align__(16) _Float16 sV[64 * LDK];      // [d][kj]  (V transposed)
    __shared__ __align__(16) _Float16 sP[4 * 32 * LDP];  // per wave: [qi 0..31][kj 0..63]

    // XCD-aware swizzle: XCD x gets (b,h) pairs 4x..4x+3, keeping K/V L2-resident.
    const int lin = blockIdx.x;                 // 0..1023
    const int bh  = ((lin & 7) << 2) | (lin >> 8);
    const int qt  = (lin >> 3) & 31;            // 128-row q tile index
    const int b   = bh >> 4;
    const int h   = bh & 15;

    const int t    = threadIdx.x;
    const int w    = t >> 6;        // wave 0..3
    const int lane = t & 63;
    const int c    = lane & 15;     // MFMA column / row-in-frag
    const int quad = lane >> 4;     // 0..3

    const size_t base = (size_t)b * S_LEN * ROWSTRIDE + (size_t)h * HDIM;
    const float* Qp = Q + base;
    const float* Kp = K + base;
    const float* Vp = V + base;

    const int q0 = qt * 128 + w * 32;   // this wave's first q row

    // ---- Q fragments, pre-scaled by SCALE*log2e, converted to f16 (held in regs)
    half8 qf[2][2];   // [u: qi sub-tile][s: d-step]
#pragma unroll
    for (int u = 0; u < 2; ++u)
#pragma unroll
        for (int s = 0; s < 2; ++s) {
            const float* qp = Qp + (size_t)(q0 + 16 * u + c) * ROWSTRIDE + 32 * s + 8 * quad;
            f4 a = *(const f4*)qp;
            f4 bb = *(const f4*)(qp + 4);
            half8 hf;
            hf[0] = (_Float16)(a[0] * QSCALE); hf[1] = (_Float16)(a[1] * QSCALE);
            hf[2] = (_Float16)(a[2] * QSCALE); hf[3] = (_Float16)(a[3] * QSCALE);
            hf[4] = (_Float16)(bb[0] * QSCALE); hf[5] = (_Float16)(bb[1] * QSCALE);
            hf[6] = (_Float16)(bb[2] * QSCALE); hf[7] = (_Float16)(bb[3] * QSCALE);
            qf[u][s] = hf;
        }

    // ---- staging state (prefetch next K/V tile into regs)
    f4 kpre[4], vpre[4];
    const int krow  = t >> 4;          // 0..15
    const int kcol  = (t & 15) * 4;    // 0..60 (floats)
    const int vrow4 = (t >> 4) * 4;    // kj base 0..60
    const int vcol  = (t & 15) * 4;    // d base 0..60

    auto loadTiles = [&](int i) {
        const float* kb = Kp + (size_t)(i * 64) * ROWSTRIDE;
        const float* vb = Vp + (size_t)(i * 64) * ROWSTRIDE;
#pragma unroll
        for (int p = 0; p < 4; ++p)
            kpre[p] = *(const f4*)(kb + (size_t)(krow + 16 * p) * ROWSTRIDE + kcol);
#pragma unroll
        for (int p = 0; p < 4; ++p)
            vpre[p] = *(const f4*)(vb + (size_t)(vrow4 + p) * ROWSTRIDE + vcol);
    };

    auto storeTiles = [&]() {
#pragma unroll
        for (int p = 0; p < 4; ++p) {   // K row-major
            half4 pk;
            pk[0] = (_Float16)kpre[p][0]; pk[1] = (_Float16)kpre[p][1];
            pk[2] = (_Float16)kpre[p][2]; pk[3] = (_Float16)kpre[p][3];
            *(half4*)&sK[(krow + 16 * p) * LDK + kcol] = pk;
        }
#pragma unroll
        for (int dd = 0; dd < 4; ++dd) { // V transposed: sV[d][kj], pack 4 kj
            half4 pk;
            pk[0] = (_Float16)vpre[0][dd]; pk[1] = (_Float16)vpre[1][dd];
            pk[2] = (_Float16)vpre[2][dd]; pk[3] = (_Float16)vpre[3][dd];
            *(half4*)&sV[(vcol + dd) * LDK + vrow4] = pk;
        }
    };

    // ---- accumulators
    f32x4 ot[2][4];  // O^T tiles: [u][dt], lane holds O[qi=16u+c][d=16dt+4*quad+r]
#pragma unroll
    for (int u = 0; u < 2; ++u)
#pragma unroll
        for (int dt = 0; dt < 4; ++dt) ot[u][dt] = (f32x4){0.f, 0.f, 0.f, 0.f};
    float m_run[2] = {-3.0e38f, -3.0e38f};
    float l_run[2] = {0.f, 0.f};

    const unsigned char* frow = Flags ? (Flags + ((size_t)b * 32 + qt) * 64) : nullptr;

    loadTiles(0);

    for (int i = 0; i < NKITER; ++i) {
        __syncthreads();
        storeTiles();
        __syncthreads();
        if (i + 1 < NKITER) loadTiles(i + 1);

        // ---- S^T = K * Q^T : tiles [u][kt], lane holds S^T[kj=16kt+4q+r][qi=16u+c]
        f32x4 st[2][4];
#pragma unroll
        for (int u = 0; u < 2; ++u)
#pragma unroll
            for (int kt = 0; kt < 4; ++kt) st[u][kt] = (f32x4){0.f, 0.f, 0.f, 0.f};
#pragma unroll
        for (int kt = 0; kt < 4; ++kt)
#pragma unroll
            for (int s = 0; s < 2; ++s) {
                half8 af = *(const half8*)&sK[(16 * kt + c) * LDK + 32 * s + 8 * quad];
                st[0][kt] = __builtin_amdgcn_mfma_f32_16x16x32_f16(af, qf[0][s], st[0][kt], 0, 0, 0);
                st[1][kt] = __builtin_amdgcn_mfma_f32_16x16x32_f16(af, qf[1][s], st[1][kt], 0, 0, 0);
            }

        // ---- mask (fast path: wave-uniform skip when tile is all ones)
        const bool allones = frow ? (frow[i] != 0) : false;
        if (!allones) {
            const int* mbase = Mask + (size_t)b * S_LEN * S_LEN + (size_t)i * 64;
#pragma unroll
            for (int u = 0; u < 2; ++u) {
                const int qi = q0 + 16 * u + c;
#pragma unroll
                for (int kt = 0; kt < 4; ++kt) {
                    i4 mv = *(const i4*)(mbase + (size_t)qi * S_LEN + 16 * kt + 4 * quad);
#pragma unroll
                    for (int r = 0; r < 4; ++r)
                        if (mv[r] == 0) st[u][kt][r] = MASKVAL;
                }
            }
        }

        // ---- online softmax (qi == lane column; kj spread over quads+regs)
#pragma unroll
        for (int u = 0; u < 2; ++u) {
            float mx = st[u][0][0];
#pragma unroll
            for (int kt = 0; kt < 4; ++kt)
#pragma unroll
                for (int r = 0; r < 4; ++r) mx = fmaxf(mx, st[u][kt][r]);
            mx = fmaxf(mx, __shfl_xor(mx, 16));
            mx = fmaxf(mx, __shfl_xor(mx, 32));
            const float mnew  = fmaxf(m_run[u], mx);
            const float alpha = EXP2(m_run[u] - mnew);
            m_run[u] = mnew;
            float rsum = 0.f;
#pragma unroll
            for (int kt = 0; kt < 4; ++kt) {
                half4 pk;
#pragma unroll
                for (int r = 0; r < 4; ++r) {
                    float p = EXP2(st[u][kt][r] - mnew);
                    rsum += p;
                    pk[r] = (_Float16)p;
                }
                // P row-major [qi][kj] in this wave's private strip: 4 consecutive kj
                *(half4*)&sP[(w * 32 + 16 * u + c) * LDP + 16 * kt + 4 * quad] = pk;
            }
            rsum += __shfl_xor(rsum, 16);
            rsum += __shfl_xor(rsum, 32);
            l_run[u] = l_run[u] * alpha + rsum;
#pragma unroll
            for (int dt = 0; dt < 4; ++dt) {
                ot[u][dt][0] *= alpha; ot[u][dt][1] *= alpha;
                ot[u][dt][2] *= alpha; ot[u][dt][3] *= alpha;
            }
        }

        // ---- O^T += V^T * P^T  (A = V^T frag from sV, B = P^T frag from sP)
#pragma unroll
        for (int s2 = 0; s2 < 2; ++s2) {
            half8 b0 = *(const half8*)&sP[(w * 32 + 0  + c) * LDP + 32 * s2 + 8 * quad];
            half8 b1 = *(const half8*)&sP[(w * 32 + 16 + c) * LDP + 32 * s2 + 8 * quad];
#pragma unroll
            for (int dt = 0; dt < 4; ++dt) {
                half8 vf = *(const half8*)&sV[(16 * dt + c) * LDK + 32 * s2 + 8 * quad];
                ot[0][dt] = __builtin_amdgcn_mfma_f32_16x16x32_f16(vf, b0, ot[0][dt], 0, 0, 0);
                ot[1][dt] = __builtin_amdgcn_mfma_f32_16x16x32_f16(vf, b1, ot[1][dt], 0, 0, 0);
            }
        }
    }

    // ---- epilogue: normalize by l and store (lane holds 4 consecutive d)
#pragma unroll
    for (int u = 0; u < 2; ++u) {
        const float inv = 1.0f / l_run[u];
        float* orow = Out + (size_t)(b * S_LEN + q0 + 16 * u + c) * ROWSTRIDE + h * HDIM;
#pragma unroll
        for (int dt = 0; dt < 4; ++dt) {
            f4 o;
            o[0] = ot[u][dt][0] * inv; o[1] = ot[u][dt][1] * inv;
            o[2] = ot[u][dt][2] * inv; o[3] = ot[u][dt][3] * inv;
            *(f4*)(orow + 16 * dt + 4 * quad) = o;
        }
    }
}

// =======================================================================
extern "C" void kernel_launch(void* const* d_in, const int* in_sizes, int n_in,
                              void* d_out, int out_size, void* d_ws, size_t ws_size,
                              hipStream_t stream)
{
    const float* q    = (const float*)d_in[0];
    const float* k    = (const float*)d_in[1];
    const float* v    = (const float*)d_in[2];
    const int*   mask = (const int*)d_in[3];
    float*       out  = (float*)d_out;

    unsigned char* flags = nullptr;
    if (ws_size >= 4096) {
        flags = (unsigned char*)d_ws;
        hipLaunchKernelGGL(fa_maskflags, dim3(64, 32, 2), dim3(256), 0, stream, mask, flags);
    }
    hipLaunchKernelGGL(fa_fwd, dim3(1024), dim3(256), 0, stream,
                       q, k, v, mask, flags, out);
}